// Round 11
// baseline (306.432 us; speedup 1.0000x reference)
//
#include <hip/hip_runtime.h>
#include <hip/hip_fp16.h>

// MPLayer: y[b,v] += p[r]*x[b,u]; y[b,u] += p[r]*x[b,v]  per edge (u,v), relation r.
// R=64, E=100000, N=1000000, B=4.
//
// R11: R10 two-stage sort (src-major -> dst-major, no random global gathers),
// with INDEX-STAGED flushes: LDS stages only a 2B sorted permutation index;
// payloads are recomputed at flush from the L1/L2-hot chunk window. Cuts
// msgbuild LDS 125KB->~59KB (2 blocks/CU, full occupancy) and srcbin to ~26KB.
// Within-segment record order becomes placement-order-dependent, but accum is
// exact-integer and commutative over a deterministic multiset -> y deterministic.

constexpr int  R_   = 64;
constexpr long E_   = 100000;
constexpr int  N_   = 1000000;
constexpr long RE_  = (long)R_ * E_;               // 6.4M edges
constexpr long M2_  = 2 * RE_;                     // 12.8M messages
constexpr int  BSH  = 11;
constexpr int  BUCKET = 1 << BSH;                  // 2048 entities / bucket
constexpr int  NB   = (N_ + BUCKET - 1) >> BSH;    // 489 buckets
constexpr int  NBP  = 512;                         // padded for scans
constexpr int  EPB  = 4096;                        // edges per hist/srcbin block
constexpr int  HB   = (int)((RE_ + EPB - 1) / EPB);// 1563 blocks
constexpr int  RPB  = 2 * EPB;                     // 8192 records / srcbin block
constexpr int  CH   = 16384;                       // msgbuild chunk (records)

// ---------- hist / scan machinery (R8-proven) ----------

__global__ __launch_bounds__(256) void k_hist(const int2* __restrict__ edges,
                                              int* __restrict__ g_bcnt) {
    __shared__ int lc[NB];
    for (int i = threadIdx.x; i < NB; i += 256) lc[i] = 0;
    __syncthreads();
    long k0 = (long)blockIdx.x * EPB;
    int lim = (int)min((long)EPB, RE_ - k0);
    for (int i = threadIdx.x; i < lim; i += 256) {
        int2 e = edges[k0 + i];
        atomicAdd(&lc[e.y >> BSH], 1);
        atomicAdd(&lc[e.x >> BSH], 1);
    }
    __syncthreads();
    for (int c = threadIdx.x; c < NB; c += 256)
        g_bcnt[(size_t)c * HB + blockIdx.x] = lc[c];
}

__global__ __launch_bounds__(256) void k_cellscan(const int* __restrict__ g_bcnt,
                                                  int* __restrict__ g_bbase,
                                                  int* __restrict__ ctot) {
    __shared__ int sA[256], sB[256];
    const int c = blockIdx.x, t = threadIdx.x;
    int run = 0;
    for (int chunk = 0; chunk < HB; chunk += 256) {
        int b = chunk + t;
        int v = (b < HB) ? g_bcnt[(size_t)c * HB + b] : 0;
        sA[t] = v;
        __syncthreads();
        int* A = sA; int* B = sB;
        for (int off = 1; off < 256; off <<= 1) {
            int xv = A[t];
            if (t >= off) xv += A[t - off];
            B[t] = xv;
            __syncthreads();
            int* tmp = A; A = B; B = tmp;
        }
        int incl = A[t];
        if (b < HB) g_bbase[(size_t)c * HB + b] = run + incl - v;
        run += A[255];
        __syncthreads();
    }
    if (t == 0) ctot[c] = run;
}

__global__ __launch_bounds__(512) void k_scan(const int* __restrict__ ctot,
                                              int* __restrict__ cbase) {
    __shared__ int sA[NBP], sB[NBP];
    int t = threadIdx.x;
    sA[t] = (t < NB) ? ctot[t] : 0;
    __syncthreads();
    int* A = sA; int* B = sB;
    for (int off = 1; off < NBP; off <<= 1) {
        int xv = A[t];
        if (t >= off) xv += A[t - off];
        B[t] = xv;
        __syncthreads();
        int* tmp = A; A = B; B = tmp;
    }
    if (t < NB) cbase[t] = t ? A[t - 1] : 0;
    if (t == 0) cbase[NB] = A[NB - 1];
}

// ---------- stage 1: sort bare records by SRC bucket (index-staged flush) ----------

__global__ __launch_bounds__(1024) void k_srcbin(const int2* __restrict__ edges,
                                                 const int* __restrict__ g_bcnt,
                                                 const int* __restrict__ g_bbase,
                                                 const int* __restrict__ cbase,
                                                 unsigned short* __restrict__ g_sl,
                                                 unsigned* __restrict__ g_dr) {
    __shared__ unsigned short l_idx[RPB];  // 16 KB: sorted permutation
    __shared__ int sA[NBP], sB[NBP];       // 4 KB
    __shared__ int excl[NB], cur[NB], gbase[NB];  // 6 KB
    const int t = threadIdx.x, blk = blockIdx.x;
    if (t < NBP) {
        int v = 0;
        if (t < NB) {
            v = g_bcnt[(size_t)t * HB + blk];
            gbase[t] = cbase[t] + g_bbase[(size_t)t * HB + blk];
        }
        sA[t] = v;
    }
    __syncthreads();
    int* A = sA; int* B = sB;
    for (int off = 1; off < NBP; off <<= 1) {
        if (t < NBP) { int v = A[t]; if (t >= off) v += A[t - off]; B[t] = v; }
        __syncthreads();
        int* tmp = A; A = B; B = tmp;
    }
    if (t < NB) { int e = t ? A[t - 1] : 0; excl[t] = e; cur[t] = e; }
    __syncthreads();

    const long k0 = (long)blk * EPB;
    const int lim = (int)min((long)EPB, RE_ - k0);
    // place indices (sorted by src cell) -- 4 edges per thread max
    #pragma unroll
    for (int j = 0; j < EPB / 1024; ++j) {
        int i = t + j * 1024;
        if (i < lim) {
            int2 e = edges[k0 + i];
            int p1 = atomicAdd(&cur[e.x >> BSH], 1);
            l_idx[p1] = (unsigned short)(2 * i);       // msg u->v (src u)
            int p2 = atomicAdd(&cur[e.y >> BSH], 1);
            l_idx[p2] = (unsigned short)(2 * i + 1);   // msg v->u (src v)
        }
    }
    __syncthreads();
    // coalesced flush; edges re-read from the 32KB window (L1/L2-hot)
    const int total = 2 * lim;
    #pragma unroll 4
    for (int s = t; s < total; s += 1024) {
        int idx = l_idx[s];
        int i = idx >> 1;
        int2 e = edges[k0 + i];
        unsigned r = (unsigned)(k0 + i) / (unsigned)E_;
        int src, dst;
        if (idx & 1) { src = e.y; dst = e.x; } else { src = e.x; dst = e.y; }
        int c = src >> BSH;
        int pos = gbase[c] + (s - excl[c]);
        g_sl[pos] = (unsigned short)(src & (BUCKET - 1));
        __builtin_nontemporal_store((unsigned)dst | (r << 20), g_dr + pos);
    }
}

// ---------- pair matrix: per (dst-cell, src-cell) counts -> bases ----------

__global__ __launch_bounds__(256) void k_pairhist(const unsigned* __restrict__ g_dr,
                                                  const int* __restrict__ cbase,
                                                  int* __restrict__ pairT) {
    __shared__ int lc[NB];
    const int s = blockIdx.x, t = threadIdx.x;
    for (int i = t; i < NB; i += 256) lc[i] = 0;
    __syncthreads();
    const int lo = cbase[s], hi = cbase[s + 1];
    for (int i = lo + t; i < hi; i += 256) {
        int d = (int)((g_dr[i] & 0xFFFFFu) >> BSH);
        atomicAdd(&lc[d], 1);
    }
    __syncthreads();
    for (int d = t; d < NB; d += 256) pairT[(size_t)d * NB + s] = lc[d];
}

__global__ __launch_bounds__(512) void k_pairscan(const int* __restrict__ cbase,
                                                  int* __restrict__ pairT) {
    __shared__ int sA[NBP], sB[NBP];
    const int d = blockIdx.x, t = threadIdx.x;
    sA[t] = (t < NB) ? pairT[(size_t)d * NB + t] : 0;
    __syncthreads();
    int* A = sA; int* B = sB;
    for (int off = 1; off < NBP; off <<= 1) {
        int v = A[t]; if (t >= off) v += A[t - off]; B[t] = v;
        __syncthreads();
        int* tmp = A; A = B; B = tmp;
    }
    if (t < NB) pairT[(size_t)d * NB + t] = cbase[d] + (t ? A[t - 1] : 0);
}

// ---------- stage 2: payload build (sequential x) + dst sort, index-staged ----------

__global__ __launch_bounds__(1024) void k_msgbuild(const unsigned* __restrict__ g_dr,
                                                   const unsigned short* __restrict__ g_sl,
                                                   const int* __restrict__ cbase,
                                                   const int* __restrict__ pairT,
                                                   const float* __restrict__ p,
                                                   const float* __restrict__ x,
                                                   unsigned short* __restrict__ g_dst2,
                                                   unsigned long long* __restrict__ g_pay2) {
    __shared__ unsigned short l_idx[CH];   // 32 KB: sorted permutation
    __shared__ uint2 xl[BUCKET];           // 16 KB: fp16x4 x rows (this src bucket)
    __shared__ int sA[NBP], sB[NBP];       // 4 KB
    __shared__ int excl[NB], cur[NB], runbase[NB];  // 6 KB
    __shared__ float pl[R_];
    const int t = threadIdx.x, s = blockIdx.x;
    if (t < R_) pl[t] = p[t];
    for (int j = t; j < BUCKET; j += 1024) {
        int g = (s << BSH) + j;
        float v0 = 0.f, v1 = 0.f, v2 = 0.f, v3 = 0.f;
        if (g < N_) {
            v0 = x[g]; v1 = x[(long)N_ + g]; v2 = x[2L * N_ + g]; v3 = x[3L * N_ + g];
        }
        __half2 a = __floats2half2_rn(v0, v1);
        __half2 b = __floats2half2_rn(v2, v3);
        xl[j] = make_uint2(__builtin_bit_cast(unsigned, a),
                           __builtin_bit_cast(unsigned, b));
    }
    for (int d = t; d < NB; d += 1024) runbase[d] = pairT[(size_t)d * NB + s];
    __syncthreads();

    const int lo = cbase[s], hi = cbase[s + 1];
    for (int i0 = lo; i0 < hi; i0 += CH) {
        const int cn = min(CH, hi - i0);
        if (t < NBP) sA[t] = 0;
        __syncthreads();
        // pass A: count cells (hold cell per held record)
        unsigned short mc[CH / 1024];
        #pragma unroll
        for (int j = 0; j < CH / 1024; ++j) {
            int k = t + j * 1024;
            mc[j] = 0xFFFF;
            if (k < cn) {
                int c = (int)((g_dr[i0 + k] & 0xFFFFFu) >> BSH);
                mc[j] = (unsigned short)c;
                atomicAdd(&sA[c], 1);
            }
        }
        __syncthreads();
        // scan cell counts
        {
            int* A = sA; int* B = sB;
            for (int off = 1; off < NBP; off <<= 1) {
                if (t < NBP) { int v = A[t]; if (t >= off) v += A[t - off]; B[t] = v; }
                __syncthreads();
                int* tmp = A; A = B; B = tmp;
            }
            if (t < NB) { int e = t ? A[t - 1] : 0; excl[t] = e; cur[t] = e; }
        }
        __syncthreads();
        // pass B: place sorted permutation indices
        #pragma unroll
        for (int j = 0; j < CH / 1024; ++j) {
            if (mc[j] != 0xFFFF) {
                int pos = atomicAdd(&cur[mc[j]], 1);
                l_idx[pos] = (unsigned short)(t + j * 1024);
            }
        }
        __syncthreads();
        // flush: recompute payload from L1/L2-hot window; coalesced writes
        #pragma unroll 4
        for (int s2 = t; s2 < cn; s2 += 1024) {
            int idx = l_idx[s2];
            unsigned dr = g_dr[i0 + idx];
            unsigned short sl = g_sl[i0 + idx];
            unsigned dst = dr & 0xFFFFFu;
            int c = (int)(dst >> BSH);
            float w = pl[dr >> 20];
            uint2 xv = xl[sl];
            __half2 h0 = __builtin_bit_cast(__half2, xv.x);
            __half2 h1 = __builtin_bit_cast(__half2, xv.y);
            unsigned plo = __builtin_bit_cast(unsigned,
                __floats2half2_rn(w * __low2float(h0), w * __high2float(h0)));
            unsigned phi = __builtin_bit_cast(unsigned,
                __floats2half2_rn(w * __low2float(h1), w * __high2float(h1)));
            int gpos = runbase[c] + (s2 - excl[c]);
            g_dst2[gpos] = (unsigned short)(dst & (BUCKET - 1));
            __builtin_nontemporal_store(((unsigned long long)phi << 32) | plo,
                                        g_pay2 + gpos);
        }
        __syncthreads();
        for (int d = t; d < NB; d += 1024) runbase[d] += cur[d] - excl[d];
        __syncthreads();
    }
}

// ---------- accum: packed-u64 fixed point (R8-proven, order-independent) ----------

__global__ __launch_bounds__(1024) void k_accum(const unsigned short* __restrict__ g_dst,
                                                const uint2* __restrict__ g_pay,
                                                const int* __restrict__ cbase,
                                                float* __restrict__ y) {
    __shared__ unsigned long long accA[BUCKET];
    __shared__ unsigned long long accB[BUCKET];
    const int t = threadIdx.x, b = blockIdx.x;
    for (int i = t; i < BUCKET; i += 1024) { accA[i] = 0ull; accB[i] = 0ull; }
    __syncthreads();
    const int lo = cbase[b], hi = cbase[b + 1];
    for (int i = lo + t; i < hi; i += 1024) {
        int dl = (int)g_dst[i];
        uint2 pay = g_pay[i];
        __half2 h01 = __builtin_bit_cast(__half2, pay.x);
        __half2 h23 = __builtin_bit_cast(__half2, pay.y);
        float f0 = fminf(fmaxf(__low2float(h01),  -31.f), 31.f);
        float f1 = fminf(fmaxf(__high2float(h01), -31.f), 31.f);
        float f2 = fminf(fmaxf(__low2float(h23),  -31.f), 31.f);
        float f3 = fminf(fmaxf(__high2float(h23), -31.f), 31.f);
        unsigned e0 = (unsigned)(__float2int_rn(f0 * 65536.f) + (1 << 21));
        unsigned e1 = (unsigned)(__float2int_rn(f1 * 65536.f) + (1 << 21));
        unsigned e2 = (unsigned)(__float2int_rn(f2 * 65536.f) + (1 << 21));
        unsigned e3 = (unsigned)(__float2int_rn(f3 * 65536.f) + (1 << 21));
        unsigned long long va = (unsigned long long)e0
                              | ((unsigned long long)e1 << 28)
                              | (1ull << 56);
        unsigned long long vb = (unsigned long long)e2
                              | ((unsigned long long)e3 << 28);
        atomicAdd(&accA[dl], va);
        atomicAdd(&accB[dl], vb);
    }
    __syncthreads();
    const int base_e = b << BSH;
    for (int j = t; j < BUCKET; j += 1024) {
        int i = base_e + j;
        if (i < N_) {
            unsigned long long a = accA[j], bb = accB[j];
            long deg  = (long)(a >> 56);
            long bias = deg << 21;
            long c0 = (long)(a & 0xFFFFFFFull) - bias;
            long c1 = (long)((a >> 28) & 0xFFFFFFFull) - bias;
            long c2 = (long)(bb & 0xFFFFFFFull) - bias;
            long c3 = (long)((bb >> 28) & 0xFFFFFFFull) - bias;
            const float sc = 1.f / 65536.f;
            y[i]            = (float)c0 * sc;
            y[(long)N_ + i] = (float)c1 * sc;
            y[2L * N_ + i]  = (float)c2 * sc;
            y[3L * N_ + i]  = (float)c3 * sc;
        }
    }
}

// ---------- fallback (direct atomics; ws-independent) ----------

__global__ __launch_bounds__(256) void k_scatter_direct(const int2* __restrict__ edges,
                                                        const float* __restrict__ p,
                                                        const float* __restrict__ x,
                                                        float* __restrict__ y) {
    const long stride = (long)gridDim.x * blockDim.x;
    for (long k = (long)blockIdx.x * blockDim.x + threadIdx.x; k < RE_; k += stride) {
        int2 e = edges[k];
        float w = p[(int)(k / E_)];
        #pragma unroll
        for (int b = 0; b < 4; ++b) {
            float xu = x[(long)b * N_ + e.x];
            float xv = x[(long)b * N_ + e.y];
            atomicAdd(&y[(long)b * N_ + e.y], w * xu);
            atomicAdd(&y[(long)b * N_ + e.x], w * xv);
        }
    }
}

extern "C" void kernel_launch(void* const* d_in, const int* in_sizes, int n_in,
                              void* d_out, int out_size, void* d_ws, size_t ws_size,
                              hipStream_t stream) {
    const float* p     = (const float*)d_in[0];
    const int*   edges = (const int*)d_in[1];
    const float* x     = (const float*)d_in[2];
    float*       y     = (float*)d_out;

    const size_t pay_bytes   = (size_t)M2_ * 8;           // 102.4 MB
    const size_t dr_bytes    = (size_t)M2_ * 4;           //  51.2 MB
    const size_t sl_bytes    = (size_t)M2_ * 2;           //  25.6 MB
    const size_t dst2_bytes  = (size_t)M2_ * 2;           //  25.6 MB
    const size_t bcnt_bytes  = (size_t)NB * HB * 4;       //   3.06 MB
    const size_t pair_bytes  = (size_t)NB * NB * 4;       //   0.96 MB
    const size_t ctot_bytes  = (size_t)NB * 4;
    const size_t cbase_bytes = (size_t)(NB + 1) * 4;

    const size_t need = pay_bytes + dr_bytes + sl_bytes + dst2_bytes
                      + 2 * bcnt_bytes + pair_bytes + ctot_bytes + cbase_bytes;

    if (ws_size >= need) {
        char* ws = (char*)d_ws;
        unsigned long long* g_pay2 = (unsigned long long*)ws;  ws += pay_bytes;
        unsigned* g_dr = (unsigned*)ws;              ws += dr_bytes;
        int* g_bcnt  = (int*)ws;                     ws += bcnt_bytes;
        int* g_bbase = (int*)ws;                     ws += bcnt_bytes;
        int* pairT   = (int*)ws;                     ws += pair_bytes;
        int* ctot    = (int*)ws;                     ws += ctot_bytes;
        int* cbase   = (int*)ws;                     ws += cbase_bytes;
        unsigned short* g_sl   = (unsigned short*)ws; ws += sl_bytes;
        unsigned short* g_dst2 = (unsigned short*)ws;

        k_hist<<<HB, 256, 0, stream>>>((const int2*)edges, g_bcnt);
        k_cellscan<<<NB, 256, 0, stream>>>(g_bcnt, g_bbase, ctot);
        k_scan<<<1, 512, 0, stream>>>(ctot, cbase);
        k_srcbin<<<HB, 1024, 0, stream>>>((const int2*)edges, g_bcnt, g_bbase,
                                          cbase, g_sl, g_dr);
        k_pairhist<<<NB, 256, 0, stream>>>((const unsigned*)g_dr, cbase, pairT);
        k_pairscan<<<NB, 512, 0, stream>>>(cbase, pairT);
        k_msgbuild<<<NB, 1024, 0, stream>>>((const unsigned*)g_dr,
                                            (const unsigned short*)g_sl,
                                            cbase, pairT, p, x, g_dst2, g_pay2);
        k_accum<<<NB, 1024, 0, stream>>>((const unsigned short*)g_dst2,
                                         (const uint2*)g_pay2, cbase, y);
    } else {
        hipMemsetAsync(y, 0, (size_t)out_size * sizeof(float), stream);
        k_scatter_direct<<<8192, 256, 0, stream>>>((const int2*)edges, p, x, y);
    }
}

// Round 12
// 287.736 us; speedup vs baseline: 1.0650x; 1.0650x over previous
//
#include <hip/hip_runtime.h>
#include <hip/hip_fp16.h>

// MPLayer: y[b,v] += p[r]*x[b,u]; y[b,u] += p[r]*x[b,v]  per edge (u,v), relation r.
// R=64, E=100000, N=1000000, B=4.
//
// R12: R8 payload-carrying counting sort, split by SRC HALF so each bin pass
// gathers from a 4 MiB slice of xTh (= one XCD L2 -> resident gathers).
// cell = (dst_bucket<<1) | src_half (978 cells). Two sequential bin passes.
// Also: bin LDS ~78KB -> 2 blocks/CU (R8 was 109KB -> 1), nt edge loads.
// Accum: bucket b = contiguous [cbase[2b], cbase[2b+2]). Exact-integer accum
// -> deterministic, absmax identical to R8 (0.125).

constexpr int  R_   = 64;
constexpr long E_   = 100000;
constexpr int  N_   = 1000000;
constexpr long RE_  = (long)R_ * E_;               // 6.4M edges
constexpr long M2_  = 2 * RE_;                     // 12.8M messages
constexpr int  BSH  = 11;
constexpr int  BUCKET = 1 << BSH;                  // 2048 entities / dst bucket
constexpr int  NB   = (N_ + BUCKET - 1) >> BSH;    // 489 dst buckets
constexpr int  NBP  = 512;                         // scan padding (dst cells)
constexpr int  SH   = 19;                          // src half: 2^19 ents = 4MiB fp16x4
constexpr int  NC2  = NB * 2;                      // 978 (dst,half) cells
constexpr int  EPB  = 4096;                        // edges per hist/bin block
constexpr int  HB   = (int)((RE_ + EPB - 1) / EPB);// 1563 blocks
constexpr int  RPB  = 5632;                        // staged records/block (avg 4096, +34 sigma)

// --- transpose x [4][N] f32 -> xTh [N] half4 (uint2) ---
__global__ __launch_bounds__(256) void k_transpose_h(const float* __restrict__ x,
                                                     uint2* __restrict__ xTh) {
    int i = blockIdx.x * 256 + threadIdx.x;
    if (i < N_) {
        __half2 a = __floats2half2_rn(x[i],           x[(long)N_ + i]);
        __half2 b = __floats2half2_rn(x[2L * N_ + i], x[3L * N_ + i]);
        xTh[i] = make_uint2(__builtin_bit_cast(unsigned, a),
                            __builtin_bit_cast(unsigned, b));
    }
}

// --- pass 1: per-(cell, block) histogram; cell = (dstbucket<<1)|srchalf ---
__global__ __launch_bounds__(256) void k_hist(const unsigned long long* __restrict__ edges8,
                                              int* __restrict__ g_bcnt) {
    __shared__ int lc[NC2];
    for (int i = threadIdx.x; i < NC2; i += 256) lc[i] = 0;
    __syncthreads();
    long k0 = (long)blockIdx.x * EPB;
    int lim = (int)min((long)EPB, RE_ - k0);
    for (int i = threadIdx.x; i < lim; i += 256) {
        unsigned long long ev = __builtin_nontemporal_load(edges8 + k0 + i);
        int u = (int)(unsigned)ev, v = (int)(ev >> 32);
        atomicAdd(&lc[((v >> BSH) << 1) | (u >> SH)], 1);   // msg u->v
        atomicAdd(&lc[((u >> BSH) << 1) | (v >> SH)], 1);   // msg v->u
    }
    __syncthreads();
    for (int c = threadIdx.x; c < NC2; c += 256)
        g_bcnt[(size_t)c * HB + blockIdx.x] = lc[c];
}

// --- pass 2a: per-cell cross-block exclusive scan (one block per cell) ---
__global__ __launch_bounds__(256) void k_cellscan(const int* __restrict__ g_bcnt,
                                                  int* __restrict__ g_bbase,
                                                  int* __restrict__ ctot) {
    __shared__ int sA[256], sB[256];
    const int c = blockIdx.x, t = threadIdx.x;
    int run = 0;
    for (int chunk = 0; chunk < HB; chunk += 256) {
        int b = chunk + t;
        int v = (b < HB) ? g_bcnt[(size_t)c * HB + b] : 0;
        sA[t] = v;
        __syncthreads();
        int* A = sA; int* B = sB;
        for (int off = 1; off < 256; off <<= 1) {
            int xv = A[t];
            if (t >= off) xv += A[t - off];
            B[t] = xv;
            __syncthreads();
            int* tmp = A; A = B; B = tmp;
        }
        int incl = A[t];
        if (b < HB) g_bbase[(size_t)c * HB + b] = run + incl - v;
        run += A[255];
        __syncthreads();
    }
    if (t == 0) ctot[c] = run;
}

// --- pass 2b: exclusive scan over the 978 cell totals (1 block) ---
__global__ __launch_bounds__(1024) void k_scan(const int* __restrict__ ctot,
                                               int* __restrict__ cbase) {
    __shared__ int sA[1024], sB[1024];
    int t = threadIdx.x;
    sA[t] = (t < NC2) ? ctot[t] : 0;
    __syncthreads();
    int* A = sA; int* B = sB;
    for (int off = 1; off < 1024; off <<= 1) {
        int xv = A[t];
        if (t >= off) xv += A[t - off];
        B[t] = xv;
        __syncthreads();
        int* tmp = A; A = B; B = tmp;
    }
    if (t < NC2) cbase[t] = t ? A[t - 1] : 0;
    if (t == 0) cbase[NC2] = A[NC2 - 1];
}

// --- pass 3 (x2): gather(4MiB L2-slice) + scale + LDS sort + coalesced flush ---
__global__ __launch_bounds__(1024) void k_bin_h(const unsigned long long* __restrict__ edges8,
                                                const float* __restrict__ p,
                                                const uint2* __restrict__ xTh,
                                                const int* __restrict__ g_bcnt,
                                                const int* __restrict__ g_bbase,
                                                const int* __restrict__ cbase,
                                                const int h,
                                                unsigned short* __restrict__ g_dst,
                                                unsigned long long* __restrict__ g_pay) {
    __shared__ int                l_dst[RPB];   // 22.5 KB (full 20b dst)
    __shared__ unsigned long long l_pay[RPB];   // 45 KB
    __shared__ int sA[NBP], sB[NBP];            // 4 KB
    __shared__ int excl[NB], cur[NB], gbase[NB];// 5.9 KB
    __shared__ float pl[R_];
    __shared__ int s_total;
    const int t = threadIdx.x, blk = blockIdx.x;

    if (t < NBP) {
        int v = 0;
        if (t < NB) {
            size_t idx = (size_t)((t << 1) | h) * HB + blk;
            v = g_bcnt[idx];
            gbase[t] = cbase[(t << 1) | h] + g_bbase[idx];
        }
        sA[t] = v;
    }
    if (t < R_) pl[t] = p[t];
    __syncthreads();
    int* A = sA; int* B = sB;
    for (int off = 1; off < NBP; off <<= 1) {
        if (t < NBP) { int v = A[t]; if (t >= off) v += A[t - off]; B[t] = v; }
        __syncthreads();
        int* tmp = A; A = B; B = tmp;
    }
    if (t < NB) { int e = t ? A[t - 1] : 0; excl[t] = e; cur[t] = e; }
    if (t == 0) s_total = A[NB - 1];
    __syncthreads();

    const long k0 = (long)blk * EPB;
    const int lim = (int)min((long)EPB, RE_ - k0);
    #pragma unroll
    for (int j = 0; j < EPB / 1024; ++j) {
        int i = t + j * 1024;
        if (i < lim) {
            unsigned long long ev = __builtin_nontemporal_load(edges8 + k0 + i);
            int u = (int)(unsigned)ev, v = (int)(ev >> 32);
            float w = pl[(unsigned)(k0 + i) / (unsigned)E_];
            if ((u >> SH) == h) {               // msg u->v: gather x[u]
                uint2 xv = xTh[u];
                __half2 h0 = __builtin_bit_cast(__half2, xv.x);
                __half2 h1 = __builtin_bit_cast(__half2, xv.y);
                unsigned plo = __builtin_bit_cast(unsigned,
                    __floats2half2_rn(w * __low2float(h0), w * __high2float(h0)));
                unsigned phi = __builtin_bit_cast(unsigned,
                    __floats2half2_rn(w * __low2float(h1), w * __high2float(h1)));
                int pos = atomicAdd(&cur[v >> BSH], 1);
                if (pos < RPB) {
                    l_dst[pos] = v;
                    l_pay[pos] = ((unsigned long long)phi << 32) | plo;
                }
            }
            if ((v >> SH) == h) {               // msg v->u: gather x[v]
                uint2 xv = xTh[v];
                __half2 h0 = __builtin_bit_cast(__half2, xv.x);
                __half2 h1 = __builtin_bit_cast(__half2, xv.y);
                unsigned plo = __builtin_bit_cast(unsigned,
                    __floats2half2_rn(w * __low2float(h0), w * __high2float(h0)));
                unsigned phi = __builtin_bit_cast(unsigned,
                    __floats2half2_rn(w * __low2float(h1), w * __high2float(h1)));
                int pos = atomicAdd(&cur[u >> BSH], 1);
                if (pos < RPB) {
                    l_dst[pos] = u;
                    l_pay[pos] = ((unsigned long long)phi << 32) | plo;
                }
            }
        }
    }
    __syncthreads();
    const int total = s_total;
    for (int s = t; s < total; s += 1024) {
        int dst = l_dst[s];
        int d = dst >> BSH;
        int pos = gbase[d] + (s - excl[d]);
        g_dst[pos] = (unsigned short)(dst & (BUCKET - 1));
        __builtin_nontemporal_store(l_pay[s], g_pay + pos);
    }
}

// --- pass 4: one block per dst bucket; packed-u64 fixed-point LDS accum ---
// u64A = c0[27:0] | c1[55:28] | deg[63:56];  u64B = c2[27:0] | c3[55:28]
// comp: round(f*2^16) + 2^21 (|f|<32 clamped); deg<=255; fields stay <2^28.
__global__ __launch_bounds__(1024) void k_accum(const unsigned short* __restrict__ g_dst,
                                                const unsigned long long* __restrict__ g_pay,
                                                const int* __restrict__ cbase,
                                                float* __restrict__ y) {
    __shared__ unsigned long long accA[BUCKET];
    __shared__ unsigned long long accB[BUCKET];
    const int t = threadIdx.x, b = blockIdx.x;
    for (int i = t; i < BUCKET; i += 1024) { accA[i] = 0ull; accB[i] = 0ull; }
    __syncthreads();
    const int lo = cbase[2 * b], hi = cbase[2 * b + 2];
    for (int i = lo + t; i < hi; i += 1024) {
        int dl = (int)g_dst[i];
        unsigned long long pay = __builtin_nontemporal_load(g_pay + i);
        __half2 h01 = __builtin_bit_cast(__half2, (unsigned)pay);
        __half2 h23 = __builtin_bit_cast(__half2, (unsigned)(pay >> 32));
        float f0 = fminf(fmaxf(__low2float(h01),  -31.f), 31.f);
        float f1 = fminf(fmaxf(__high2float(h01), -31.f), 31.f);
        float f2 = fminf(fmaxf(__low2float(h23),  -31.f), 31.f);
        float f3 = fminf(fmaxf(__high2float(h23), -31.f), 31.f);
        unsigned e0 = (unsigned)(__float2int_rn(f0 * 65536.f) + (1 << 21));
        unsigned e1 = (unsigned)(__float2int_rn(f1 * 65536.f) + (1 << 21));
        unsigned e2 = (unsigned)(__float2int_rn(f2 * 65536.f) + (1 << 21));
        unsigned e3 = (unsigned)(__float2int_rn(f3 * 65536.f) + (1 << 21));
        unsigned long long va = (unsigned long long)e0
                              | ((unsigned long long)e1 << 28)
                              | (1ull << 56);
        unsigned long long vb = (unsigned long long)e2
                              | ((unsigned long long)e3 << 28);
        atomicAdd(&accA[dl], va);
        atomicAdd(&accB[dl], vb);
    }
    __syncthreads();
    const int base_e = b << BSH;
    for (int j = t; j < BUCKET; j += 1024) {
        int i = base_e + j;
        if (i < N_) {
            unsigned long long a = accA[j], bb = accB[j];
            long deg  = (long)(a >> 56);
            long bias = deg << 21;
            long c0 = (long)(a & 0xFFFFFFFull) - bias;
            long c1 = (long)((a >> 28) & 0xFFFFFFFull) - bias;
            long c2 = (long)(bb & 0xFFFFFFFull) - bias;
            long c3 = (long)((bb >> 28) & 0xFFFFFFFull) - bias;
            const float sc = 1.f / 65536.f;
            y[i]            = (float)c0 * sc;
            y[(long)N_ + i] = (float)c1 * sc;
            y[2L * N_ + i]  = (float)c2 * sc;
            y[3L * N_ + i]  = (float)c3 * sc;
        }
    }
}

// ---------- fallback (direct atomics; ws-independent) ----------
__global__ __launch_bounds__(256) void k_scatter_direct(const int2* __restrict__ edges,
                                                        const float* __restrict__ p,
                                                        const float* __restrict__ x,
                                                        float* __restrict__ y) {
    const long stride = (long)gridDim.x * blockDim.x;
    for (long k = (long)blockIdx.x * blockDim.x + threadIdx.x; k < RE_; k += stride) {
        int2 e = edges[k];
        float w = p[(int)(k / E_)];
        #pragma unroll
        for (int b = 0; b < 4; ++b) {
            float xu = x[(long)b * N_ + e.x];
            float xv = x[(long)b * N_ + e.y];
            atomicAdd(&y[(long)b * N_ + e.y], w * xu);
            atomicAdd(&y[(long)b * N_ + e.x], w * xv);
        }
    }
}

extern "C" void kernel_launch(void* const* d_in, const int* in_sizes, int n_in,
                              void* d_out, int out_size, void* d_ws, size_t ws_size,
                              hipStream_t stream) {
    const float* p     = (const float*)d_in[0];
    const int*   edges = (const int*)d_in[1];
    const float* x     = (const float*)d_in[2];
    float*       y     = (float*)d_out;

    const size_t xTh_bytes   = (size_t)N_ * 8;            //   8.0 MB
    const size_t pay_bytes   = (size_t)M2_ * 8;           // 102.4 MB
    const size_t dst_bytes   = (size_t)M2_ * 2;           //  25.6 MB
    const size_t bcnt_bytes  = (size_t)NC2 * HB * 4;      //   6.1 MB
    const size_t ctot_bytes  = (size_t)NC2 * 4;
    const size_t cbase_bytes = (size_t)(NC2 + 1) * 4;
    const size_t need = xTh_bytes + pay_bytes + dst_bytes + 2 * bcnt_bytes
                      + ctot_bytes + cbase_bytes;

    if (ws_size >= need) {
        char* ws = (char*)d_ws;
        uint2* xTh = (uint2*)ws;                       ws += xTh_bytes;
        unsigned long long* g_pay = (unsigned long long*)ws;  ws += pay_bytes;
        int* g_bcnt  = (int*)ws;                       ws += bcnt_bytes;
        int* g_bbase = (int*)ws;                       ws += bcnt_bytes;
        int* ctot    = (int*)ws;                       ws += ctot_bytes;
        int* cbase   = (int*)ws;                       ws += cbase_bytes;
        unsigned short* g_dst = (unsigned short*)ws;

        k_transpose_h<<<(N_ + 255) / 256, 256, 0, stream>>>(x, xTh);
        k_hist<<<HB, 256, 0, stream>>>((const unsigned long long*)edges, g_bcnt);
        k_cellscan<<<NC2, 256, 0, stream>>>(g_bcnt, g_bbase, ctot);
        k_scan<<<1, 1024, 0, stream>>>(ctot, cbase);
        k_bin_h<<<HB, 1024, 0, stream>>>((const unsigned long long*)edges, p,
                                         (const uint2*)xTh, g_bcnt, g_bbase,
                                         cbase, 0, g_dst, g_pay);
        k_bin_h<<<HB, 1024, 0, stream>>>((const unsigned long long*)edges, p,
                                         (const uint2*)xTh, g_bcnt, g_bbase,
                                         cbase, 1, g_dst, g_pay);
        k_accum<<<NB, 1024, 0, stream>>>((const unsigned short*)g_dst,
                                         (const unsigned long long*)g_pay, cbase, y);
    } else {
        hipMemsetAsync(y, 0, (size_t)out_size * sizeof(float), stream);
        k_scatter_direct<<<8192, 256, 0, stream>>>((const int2*)edges, p, x, y);
    }
}

// Round 14
// 283.290 us; speedup vs baseline: 1.0817x; 1.0157x over previous
//
#include <hip/hip_runtime.h>
#include <hip/hip_fp16.h>

// MPLayer: y[b,v] += p[r]*x[b,u]; y[b,u] += p[r]*x[b,v]  per edge (u,v), relation r.
// R=64, E=100000, N=1000000, B=4.
//
// R13 (retry; previous round died to an infra fault before producing data):
// two-stage sort with slab-claimed flushes.
//  srcbin  : sort messages {src, dst|r<<20} by SRC bucket. Pure stream.
//  msgbuild: 1563 blocks x 8192 consecutive src-sorted messages; gathers hit a
//            ~16-64KB L2-hot window. Payload fp16x4, then LDS sort by DST
//            bucket, flush to slab positions claimed from g_tailB.
//  accum   : packed-u64 fixed-point LDS accumulate (exact integer, commutative
//            -> y deterministic despite schedule-dependent record placement).
// One cbase serves src- AND dst-major layouts (twin-message symmetry).

constexpr int  R_   = 64;
constexpr long E_   = 100000;
constexpr int  N_   = 1000000;
constexpr long RE_  = (long)R_ * E_;               // 6.4M edges
constexpr long M2_  = 2 * RE_;                     // 12.8M messages
constexpr int  BSH  = 11;
constexpr int  BUCKET = 1 << BSH;                  // 2048 entities / bucket
constexpr int  NB   = (N_ + BUCKET - 1) >> BSH;    // 489 buckets
constexpr int  NBP  = 512;                         // scan padding
constexpr int  EPB  = 4096;                        // edges per hist/srcbin block
constexpr int  HB   = (int)((RE_ + EPB - 1) / EPB);// 1563 blocks
constexpr int  RPB  = 2 * EPB;                     // 8192 staged records (exact)
constexpr int  MCH  = 8192;                        // messages per msgbuild chunk
constexpr int  MBB  = (int)((M2_ + MCH - 1) / MCH);// 1563 chunks

// --- transpose x [4][N] f32 -> xTh [N] half4 (uint2) ---
__global__ __launch_bounds__(256) void k_transpose_h(const float* __restrict__ x,
                                                     uint2* __restrict__ xTh) {
    int i = blockIdx.x * 256 + threadIdx.x;
    if (i < N_) {
        __half2 a = __floats2half2_rn(x[i],           x[(long)N_ + i]);
        __half2 b = __floats2half2_rn(x[2L * N_ + i], x[3L * N_ + i]);
        xTh[i] = make_uint2(__builtin_bit_cast(unsigned, a),
                            __builtin_bit_cast(unsigned, b));
    }
}

// --- per-(cell, block) histogram of message src-cells (== dst-cells) ---
__global__ __launch_bounds__(256) void k_hist(const unsigned long long* __restrict__ edges8,
                                              int* __restrict__ g_bcnt) {
    __shared__ int lc[NB];
    for (int i = threadIdx.x; i < NB; i += 256) lc[i] = 0;
    __syncthreads();
    long k0 = (long)blockIdx.x * EPB;
    int lim = (int)min((long)EPB, RE_ - k0);
    for (int i = threadIdx.x; i < lim; i += 256) {
        unsigned long long ev = __builtin_nontemporal_load(edges8 + k0 + i);
        unsigned u = (unsigned)ev, v = (unsigned)(ev >> 32);
        atomicAdd(&lc[u >> BSH], 1);
        atomicAdd(&lc[v >> BSH], 1);
    }
    __syncthreads();
    for (int c = threadIdx.x; c < NB; c += 256)
        g_bcnt[(size_t)c * HB + blockIdx.x] = lc[c];
}

// --- per-cell totals: one block per cell, coalesced row reduction ---
__global__ __launch_bounds__(256) void k_colsum(const int* __restrict__ g_bcnt,
                                                int* __restrict__ ctot) {
    __shared__ int red[256];
    const int c = blockIdx.x, t = threadIdx.x;
    int s = 0;
    for (int b = t; b < HB; b += 256) s += g_bcnt[(size_t)c * HB + b];
    red[t] = s;
    __syncthreads();
    for (int off = 128; off > 0; off >>= 1) {
        if (t < off) red[t] += red[t + off];
        __syncthreads();
    }
    if (t == 0) ctot[c] = red[0];
}

// --- exclusive scan of 489 cell totals; init both tail arrays ---
__global__ __launch_bounds__(512) void k_scan(const int* __restrict__ ctot,
                                              int* __restrict__ cbase,
                                              int* __restrict__ tailA,
                                              int* __restrict__ tailB) {
    __shared__ int sA[NBP], sB[NBP];
    int t = threadIdx.x;
    sA[t] = (t < NB) ? ctot[t] : 0;
    __syncthreads();
    int* A = sA; int* B = sB;
    for (int off = 1; off < NBP; off <<= 1) {
        int v = A[t];
        if (t >= off) v += A[t - off];
        B[t] = v;
        __syncthreads();
        int* tmp = A; A = B; B = tmp;
    }
    if (t < NB) { int e = t ? A[t - 1] : 0; cbase[t] = e; tailA[t] = e; tailB[t] = e; }
    if (t == 0) cbase[NB] = A[NB - 1];
}

// --- stage A: sort messages by SRC bucket; slab-claimed coalesced flush ---
__global__ __launch_bounds__(1024) void k_srcbin(const unsigned long long* __restrict__ edges8,
                                                 const int* __restrict__ g_bcnt,
                                                 int* __restrict__ g_tailA,
                                                 unsigned short* __restrict__ g_sl,
                                                 unsigned* __restrict__ g_dr) {
    __shared__ unsigned l_src[RPB];        // 32 KB
    __shared__ unsigned l_dr[RPB];         // 32 KB
    __shared__ int sA[NBP], sB[NBP];       // 4 KB
    __shared__ int excl[NB], cur[NB], slab[NB];  // 6 KB
    const int t = threadIdx.x, blk = blockIdx.x;
    if (t < NBP) sA[t] = (t < NB) ? g_bcnt[(size_t)t * HB + blk] : 0;
    __syncthreads();
    int* A = sA; int* B = sB;
    for (int off = 1; off < NBP; off <<= 1) {
        if (t < NBP) { int v = A[t]; if (t >= off) v += A[t - off]; B[t] = v; }
        __syncthreads();
        int* tmp = A; A = B; B = tmp;
    }
    if (t < NB) { int e = t ? A[t - 1] : 0; excl[t] = e; cur[t] = e; }
    __syncthreads();

    const long k0 = (long)blk * EPB;
    const int lim = (int)min((long)EPB, RE_ - k0);
    const unsigned r0 = (unsigned)(k0 / E_);
    const long bnd = (long)(r0 + 1) * E_;      // at most one relation boundary per block
    #pragma unroll
    for (int j = 0; j < EPB / 1024; ++j) {
        int i = t + j * 1024;
        if (i < lim) {
            unsigned long long ev = __builtin_nontemporal_load(edges8 + k0 + i);
            unsigned u = (unsigned)ev, v = (unsigned)(ev >> 32);
            unsigned r = (k0 + i >= bnd) ? r0 + 1 : r0;
            int p1 = atomicAdd(&cur[u >> BSH], 1);     // msg u->v (src u)
            l_src[p1] = u;
            l_dr[p1]  = v | (r << 20);
            int p2 = atomicAdd(&cur[v >> BSH], 1);     // msg v->u (src v)
            l_src[p2] = v;
            l_dr[p2]  = u | (r << 20);
        }
    }
    __syncthreads();
    for (int c = t; c < NB; c += 1024) {
        int cnt = cur[c] - excl[c];
        slab[c] = cnt ? atomicAdd(&g_tailA[c], cnt) : 0;
    }
    __syncthreads();
    const int total = 2 * lim;
    for (int s = t; s < total; s += 1024) {
        unsigned src = l_src[s];
        int c = (int)(src >> BSH);
        int pos = slab[c] + (s - excl[c]);
        g_sl[pos] = (unsigned short)(src & (BUCKET - 1));
        __builtin_nontemporal_store(l_dr[s], g_dr + pos);
    }
}

// --- stage B: chunk-parallel payload build (L2-hot gathers) + DST sort ---
__global__ __launch_bounds__(1024) void k_msgbuild(const unsigned* __restrict__ g_dr,
                                                   const unsigned short* __restrict__ g_sl,
                                                   const int* __restrict__ cbase,
                                                   int* __restrict__ g_tailB,
                                                   const float* __restrict__ p,
                                                   const uint2* __restrict__ xTh,
                                                   unsigned short* __restrict__ g_dst2,
                                                   unsigned long long* __restrict__ g_pay2) {
    __shared__ unsigned l_dst[MCH];            // 32 KB
    __shared__ unsigned long long l_pay[MCH];  // 64 KB
    __shared__ int sA[NBP], sB[NBP];           // 4 KB
    __shared__ int excl[NB], cur[NB], slab[NB];// 6 KB
    __shared__ int cbl[NBP];                   // 2 KB cbase copy for bsearch
    __shared__ float pl[R_];
    const int t = threadIdx.x, blk = blockIdx.x;
    if (t < R_) pl[t] = p[t];
    if (t < NBP) { sA[t] = 0; cbl[t] = (t <= NB) ? cbase[t] : 0x7fffffff; }
    __syncthreads();

    const long m0 = (long)blk * MCH;
    const int lim = (int)min((long)MCH, M2_ - m0);
    unsigned mdr[MCH / 1024];
    unsigned msrc[MCH / 1024];
    // phase 1: read records, derive full src (bucket via bsearch over cbase), count dst-cells
    #pragma unroll
    for (int j = 0; j < MCH / 1024; ++j) {
        int k = t + j * 1024;
        mdr[j] = 0; msrc[j] = 0;
        if (k < lim) {
            int m = (int)(m0 + k);
            unsigned dr = __builtin_nontemporal_load(g_dr + m);
            unsigned short sl = g_sl[m];
            int lo = 0, hi = NB - 1;                       // largest b: cbl[b] <= m
            while (lo < hi) { int mid = (lo + hi + 1) >> 1; if (cbl[mid] <= m) lo = mid; else hi = mid - 1; }
            msrc[j] = ((unsigned)lo << BSH) | sl;
            mdr[j] = dr;
            atomicAdd(&sA[(dr & 0xFFFFFu) >> BSH], 1);
        }
    }
    __syncthreads();
    int* A = sA; int* B = sB;
    for (int off = 1; off < NBP; off <<= 1) {
        if (t < NBP) { int v = A[t]; if (t >= off) v += A[t - off]; B[t] = v; }
        __syncthreads();
        int* tmp = A; A = B; B = tmp;
    }
    if (t < NB) { int e = t ? A[t - 1] : 0; excl[t] = e; cur[t] = e; }
    __syncthreads();
    // phase 2: issue all gathers (L2-hot window), then payload + stage
    uint2 xg[MCH / 1024];
    #pragma unroll
    for (int j = 0; j < MCH / 1024; ++j) {
        int k = t + j * 1024;
        if (k < lim) xg[j] = xTh[msrc[j]];
    }
    #pragma unroll
    for (int j = 0; j < MCH / 1024; ++j) {
        int k = t + j * 1024;
        if (k < lim) {
            unsigned dr = mdr[j];
            float w = pl[dr >> 20];
            __half2 h0 = __builtin_bit_cast(__half2, xg[j].x);
            __half2 h1 = __builtin_bit_cast(__half2, xg[j].y);
            unsigned plo = __builtin_bit_cast(unsigned,
                __floats2half2_rn(w * __low2float(h0), w * __high2float(h0)));
            unsigned phi = __builtin_bit_cast(unsigned,
                __floats2half2_rn(w * __low2float(h1), w * __high2float(h1)));
            unsigned dst = dr & 0xFFFFFu;
            int pos = atomicAdd(&cur[dst >> BSH], 1);
            l_dst[pos] = dst;
            l_pay[pos] = ((unsigned long long)phi << 32) | plo;
        }
    }
    __syncthreads();
    for (int c = t; c < NB; c += 1024) {
        int cnt = cur[c] - excl[c];
        slab[c] = cnt ? atomicAdd(&g_tailB[c], cnt) : 0;
    }
    __syncthreads();
    for (int s = t; s < lim; s += 1024) {
        unsigned dst = l_dst[s];
        int c = (int)(dst >> BSH);
        int pos = slab[c] + (s - excl[c]);
        g_dst2[pos] = (unsigned short)(dst & (BUCKET - 1));
        __builtin_nontemporal_store(l_pay[s], g_pay2 + pos);
    }
}

// --- accum: packed-u64 fixed point (order-independent exact integer) ---
// u64A = c0[27:0] | c1[55:28] | deg[63:56];  u64B = c2[27:0] | c3[55:28]
// comp: round(f*2^16) + 2^21 (|f|<32 clamped); deg<=255; fields stay <2^28.
__global__ __launch_bounds__(1024) void k_accum(const unsigned short* __restrict__ g_dst,
                                                const unsigned long long* __restrict__ g_pay,
                                                const int* __restrict__ cbase,
                                                float* __restrict__ y) {
    __shared__ unsigned long long accA[BUCKET];
    __shared__ unsigned long long accB[BUCKET];
    const int t = threadIdx.x, b = blockIdx.x;
    for (int i = t; i < BUCKET; i += 1024) { accA[i] = 0ull; accB[i] = 0ull; }
    __syncthreads();
    const int lo = cbase[b], hi = cbase[b + 1];
    for (int i = lo + t; i < hi; i += 1024) {
        int dl = (int)g_dst[i];
        unsigned long long pay = __builtin_nontemporal_load(g_pay + i);
        __half2 h01 = __builtin_bit_cast(__half2, (unsigned)pay);
        __half2 h23 = __builtin_bit_cast(__half2, (unsigned)(pay >> 32));
        float f0 = fminf(fmaxf(__low2float(h01),  -31.f), 31.f);
        float f1 = fminf(fmaxf(__high2float(h01), -31.f), 31.f);
        float f2 = fminf(fmaxf(__low2float(h23),  -31.f), 31.f);
        float f3 = fminf(fmaxf(__high2float(h23), -31.f), 31.f);
        unsigned e0 = (unsigned)(__float2int_rn(f0 * 65536.f) + (1 << 21));
        unsigned e1 = (unsigned)(__float2int_rn(f1 * 65536.f) + (1 << 21));
        unsigned e2 = (unsigned)(__float2int_rn(f2 * 65536.f) + (1 << 21));
        unsigned e3 = (unsigned)(__float2int_rn(f3 * 65536.f) + (1 << 21));
        unsigned long long va = (unsigned long long)e0
                              | ((unsigned long long)e1 << 28)
                              | (1ull << 56);
        unsigned long long vb = (unsigned long long)e2
                              | ((unsigned long long)e3 << 28);
        atomicAdd(&accA[dl], va);
        atomicAdd(&accB[dl], vb);
    }
    __syncthreads();
    const int base_e = b << BSH;
    for (int j = t; j < BUCKET; j += 1024) {
        int i = base_e + j;
        if (i < N_) {
            unsigned long long a = accA[j], bb = accB[j];
            long deg  = (long)(a >> 56);
            long bias = deg << 21;
            long c0 = (long)(a & 0xFFFFFFFull) - bias;
            long c1 = (long)((a >> 28) & 0xFFFFFFFull) - bias;
            long c2 = (long)(bb & 0xFFFFFFFull) - bias;
            long c3 = (long)((bb >> 28) & 0xFFFFFFFull) - bias;
            const float sc = 1.f / 65536.f;
            y[i]            = (float)c0 * sc;
            y[(long)N_ + i] = (float)c1 * sc;
            y[2L * N_ + i]  = (float)c2 * sc;
            y[3L * N_ + i]  = (float)c3 * sc;
        }
    }
}

// ---------- fallback (direct atomics; ws-independent) ----------
__global__ __launch_bounds__(256) void k_scatter_direct(const int2* __restrict__ edges,
                                                        const float* __restrict__ p,
                                                        const float* __restrict__ x,
                                                        float* __restrict__ y) {
    const long stride = (long)gridDim.x * blockDim.x;
    for (long k = (long)blockIdx.x * blockDim.x + threadIdx.x; k < RE_; k += stride) {
        int2 e = edges[k];
        float w = p[(int)(k / E_)];
        #pragma unroll
        for (int b = 0; b < 4; ++b) {
            float xu = x[(long)b * N_ + e.x];
            float xv = x[(long)b * N_ + e.y];
            atomicAdd(&y[(long)b * N_ + e.y], w * xu);
            atomicAdd(&y[(long)b * N_ + e.x], w * xv);
        }
    }
}

extern "C" void kernel_launch(void* const* d_in, const int* in_sizes, int n_in,
                              void* d_out, int out_size, void* d_ws, size_t ws_size,
                              hipStream_t stream) {
    const float* p     = (const float*)d_in[0];
    const int*   edges = (const int*)d_in[1];
    const float* x     = (const float*)d_in[2];
    float*       y     = (float*)d_out;

    const size_t pay_bytes   = (size_t)M2_ * 8;           // 102.4 MB
    const size_t dr_bytes    = (size_t)M2_ * 4;           //  51.2 MB
    const size_t xTh_bytes   = (size_t)N_ * 8;            //   8.0 MB
    const size_t bcnt_bytes  = (size_t)NB * HB * 4;       //   3.06 MB
    const size_t ctot_bytes  = (size_t)NBP * 4;
    const size_t cbase_bytes = (size_t)(NB + 1) * 4;
    const size_t tail_bytes  = (size_t)NB * 4;
    const size_t sl_bytes    = (size_t)M2_ * 2;           //  25.6 MB
    const size_t dst2_bytes  = (size_t)M2_ * 2;           //  25.6 MB
    const size_t need = pay_bytes + dr_bytes + xTh_bytes + bcnt_bytes + ctot_bytes
                      + cbase_bytes + 2 * tail_bytes + sl_bytes + dst2_bytes + 64;

    if (ws_size >= need) {
        char* ws = (char*)d_ws;
        unsigned long long* g_pay2 = (unsigned long long*)ws;  ws += pay_bytes;
        unsigned* g_dr = (unsigned*)ws;               ws += dr_bytes;
        uint2*    xTh  = (uint2*)ws;                  ws += xTh_bytes;
        int* g_bcnt = (int*)ws;                       ws += bcnt_bytes;
        int* ctot   = (int*)ws;                       ws += ctot_bytes;
        int* cbase  = (int*)ws;                       ws += cbase_bytes;
        int* tailA  = (int*)ws;                       ws += tail_bytes;
        int* tailB  = (int*)ws;                       ws += tail_bytes;
        unsigned short* g_sl   = (unsigned short*)ws; ws += sl_bytes;
        unsigned short* g_dst2 = (unsigned short*)ws;

        k_transpose_h<<<(N_ + 255) / 256, 256, 0, stream>>>(x, xTh);
        k_hist<<<HB, 256, 0, stream>>>((const unsigned long long*)edges, g_bcnt);
        k_colsum<<<NB, 256, 0, stream>>>(g_bcnt, ctot);
        k_scan<<<1, 512, 0, stream>>>(ctot, cbase, tailA, tailB);
        k_srcbin<<<HB, 1024, 0, stream>>>((const unsigned long long*)edges, g_bcnt,
                                          tailA, g_sl, g_dr);
        k_msgbuild<<<MBB, 1024, 0, stream>>>((const unsigned*)g_dr,
                                             (const unsigned short*)g_sl,
                                             cbase, tailB, p, (const uint2*)xTh,
                                             g_dst2, g_pay2);
        k_accum<<<NB, 1024, 0, stream>>>((const unsigned short*)g_dst2,
                                         (const unsigned long long*)g_pay2, cbase, y);
    } else {
        hipMemsetAsync(y, 0, (size_t)out_size * sizeof(float), stream);
        k_scatter_direct<<<8192, 256, 0, stream>>>((const int2*)edges, p, x, y);
    }
}

// Round 16
// 268.462 us; speedup vs baseline: 1.1414x; 1.0552x over previous
//
#include <hip/hip_runtime.h>
#include <hip/hip_fp16.h>

// MPLayer: y[b,v] += p[r]*x[b,u]; y[b,u] += p[r]*x[b,v]  per edge (u,v), relation r.
// R=64, E=100000, N=1000000, B=4.
//
// R15 (retry; prior submit died to the same container infra fault as R13):
// two-stage sort (R13) with measured fixes:
//  srcbin  : COARSE sort by src>>14 (62 cells) -> 8x longer flush segments
//            (no partial-line RMW), 62 claims/block, local counting.
//  msgbuild: MCH=4096 (LDS ~58KB -> 2 blocks/CU); src recovered by carried
//            linear walk over 62 coarse bases (kills the 9-step bsearch).
//  accum   : packed-u64 exact-integer LDS accumulate (deterministic).
// Fine 489-bucket cbase (hist twin-symmetry) serves dst staging + accum.

constexpr int  R_   = 64;
constexpr long E_   = 100000;
constexpr int  N_   = 1000000;
constexpr long RE_  = (long)R_ * E_;               // 6.4M edges
constexpr long M2_  = 2 * RE_;                     // 12.8M messages
constexpr int  BSH  = 11;
constexpr int  BUCKET = 1 << BSH;                  // 2048 entities / dst bucket
constexpr int  NB   = (N_ + BUCKET - 1) >> BSH;    // 489 dst buckets
constexpr int  NBP  = 512;                         // scan padding
constexpr int  CSH  = 14;                          // coarse src cell: 16384 entities
constexpr int  NC   = ((N_ - 1) >> CSH) + 1;       // 62 coarse cells
constexpr int  EPB  = 4096;                        // edges per hist/srcbin block
constexpr int  HB   = (int)((RE_ + EPB - 1) / EPB);// 1563 blocks
constexpr int  RPB  = 2 * EPB;                     // 8192 staged records
constexpr int  MCH  = 4096;                        // messages per msgbuild chunk
constexpr int  MBB  = (int)((M2_ + MCH - 1) / MCH);// 3125 chunks

// --- transpose x [4][N] f32 -> xTh [N] half4 (uint2) ---
__global__ __launch_bounds__(256) void k_transpose_h(const float* __restrict__ x,
                                                     uint2* __restrict__ xTh) {
    int i = blockIdx.x * 256 + threadIdx.x;
    if (i < N_) {
        __half2 a = __floats2half2_rn(x[i],           x[(long)N_ + i]);
        __half2 b = __floats2half2_rn(x[2L * N_ + i], x[3L * N_ + i]);
        xTh[i] = make_uint2(__builtin_bit_cast(unsigned, a),
                            __builtin_bit_cast(unsigned, b));
    }
}

// --- fine per-(bucket, block) histogram (dst-bucket == src-bucket counts) ---
__global__ __launch_bounds__(256) void k_hist(const unsigned long long* __restrict__ edges8,
                                              int* __restrict__ g_bcnt) {
    __shared__ int lc[NB];
    for (int i = threadIdx.x; i < NB; i += 256) lc[i] = 0;
    __syncthreads();
    long k0 = (long)blockIdx.x * EPB;
    int lim = (int)min((long)EPB, RE_ - k0);
    for (int i = threadIdx.x; i < lim; i += 256) {
        unsigned long long ev = __builtin_nontemporal_load(edges8 + k0 + i);
        unsigned u = (unsigned)ev, v = (unsigned)(ev >> 32);
        atomicAdd(&lc[u >> BSH], 1);
        atomicAdd(&lc[v >> BSH], 1);
    }
    __syncthreads();
    for (int c = threadIdx.x; c < NB; c += 256)
        g_bcnt[(size_t)c * HB + blockIdx.x] = lc[c];
}

// --- per-cell totals ---
__global__ __launch_bounds__(256) void k_colsum(const int* __restrict__ g_bcnt,
                                                int* __restrict__ ctot) {
    __shared__ int red[256];
    const int c = blockIdx.x, t = threadIdx.x;
    int s = 0;
    for (int b = t; b < HB; b += 256) s += g_bcnt[(size_t)c * HB + b];
    red[t] = s;
    __syncthreads();
    for (int off = 128; off > 0; off >>= 1) {
        if (t < off) red[t] += red[t + off];
        __syncthreads();
    }
    if (t == 0) ctot[c] = red[0];
}

// --- scan 489 totals; init coarse tailA (tailA[c]=cbase[8c]) and fine tailB ---
__global__ __launch_bounds__(512) void k_scan(const int* __restrict__ ctot,
                                              int* __restrict__ cbase,
                                              int* __restrict__ tailA,
                                              int* __restrict__ tailB) {
    __shared__ int sA[NBP], sB[NBP];
    int t = threadIdx.x;
    sA[t] = (t < NB) ? ctot[t] : 0;
    __syncthreads();
    int* A = sA; int* B = sB;
    for (int off = 1; off < NBP; off <<= 1) {
        int v = A[t];
        if (t >= off) v += A[t - off];
        B[t] = v;
        __syncthreads();
        int* tmp = A; A = B; B = tmp;
    }
    if (t < NB) { int e = t ? A[t - 1] : 0; cbase[t] = e; tailB[t] = e; }
    if (t == 0) cbase[NB] = A[NB - 1];
    if (t < NC) {
        int f = t * 8;                      // fine index of coarse-cell start (8*61=488<=NB)
        tailA[t] = f ? A[f - 1] : 0;
    }
}

// --- stage A: coarse sort by src>>14; local counting; slab-claimed flush ---
__global__ __launch_bounds__(1024) void k_srcbin(const unsigned long long* __restrict__ edges8,
                                                 int* __restrict__ g_tailA,
                                                 unsigned short* __restrict__ g_sl,
                                                 unsigned* __restrict__ g_dr) {
    __shared__ unsigned l_src[RPB];        // 32 KB
    __shared__ unsigned l_dr[RPB];         // 32 KB
    __shared__ int sA[64], sB[64];
    __shared__ int excl[64], cur[64], slab[64];
    const int t = threadIdx.x, blk = blockIdx.x;
    if (t < 64) sA[t] = 0;
    __syncthreads();

    const long k0 = (long)blk * EPB;
    const int lim = (int)min((long)EPB, RE_ - k0);
    // pass 1: count coarse cells (edges window becomes L1/L2-hot)
    #pragma unroll
    for (int j = 0; j < EPB / 1024; ++j) {
        int i = t + j * 1024;
        if (i < lim) {
            unsigned long long ev = __builtin_nontemporal_load(edges8 + k0 + i);
            unsigned u = (unsigned)ev, v = (unsigned)(ev >> 32);
            atomicAdd(&sA[u >> CSH], 1);
            atomicAdd(&sA[v >> CSH], 1);
        }
    }
    __syncthreads();
    // scan 64 (Hillis-Steele in LDS)
    {
        int* A = sA; int* B = sB;
        for (int off = 1; off < 64; off <<= 1) {
            if (t < 64) { int v = A[t]; if (t >= off) v += A[t - off]; B[t] = v; }
            __syncthreads();
            int* tmp = A; A = B; B = tmp;
        }
        if (t < 64) { int e = t ? A[t - 1] : 0; excl[t] = e; cur[t] = e; }
    }
    __syncthreads();
    // pass 2: stage records sorted by coarse cell
    const unsigned r0 = (unsigned)(k0 / E_);
    const long bnd = (long)(r0 + 1) * E_;      // at most one relation boundary/block
    #pragma unroll
    for (int j = 0; j < EPB / 1024; ++j) {
        int i = t + j * 1024;
        if (i < lim) {
            unsigned long long ev = edges8[k0 + i];   // L1-hot re-read
            unsigned u = (unsigned)ev, v = (unsigned)(ev >> 32);
            unsigned r = (k0 + i >= bnd) ? r0 + 1 : r0;
            int p1 = atomicAdd(&cur[u >> CSH], 1);    // msg u->v (src u)
            l_src[p1] = u;
            l_dr[p1]  = v | (r << 20);
            int p2 = atomicAdd(&cur[v >> CSH], 1);    // msg v->u (src v)
            l_src[p2] = v;
            l_dr[p2]  = u | (r << 20);
        }
    }
    __syncthreads();
    if (t < NC) {
        int cnt = cur[t] - excl[t];
        slab[t] = cnt ? atomicAdd(&g_tailA[t], cnt) : 0;
    }
    __syncthreads();
    const int total = 2 * lim;
    for (int s = t; s < total; s += 1024) {
        unsigned src = l_src[s];
        int c = (int)(src >> CSH);
        int pos = slab[c] + (s - excl[c]);
        g_sl[pos] = (unsigned short)(src & ((1u << CSH) - 1));
        __builtin_nontemporal_store(l_dr[s], g_dr + pos);
    }
}

// --- stage B: chunked payload build (L2-hot gathers, no bsearch) + DST sort ---
__global__ __launch_bounds__(1024) void k_msgbuild(const unsigned* __restrict__ g_dr,
                                                   const unsigned short* __restrict__ g_sl,
                                                   const int* __restrict__ cbase,
                                                   int* __restrict__ g_tailB,
                                                   const float* __restrict__ p,
                                                   const uint2* __restrict__ xTh,
                                                   unsigned short* __restrict__ g_dst2,
                                                   unsigned long long* __restrict__ g_pay2) {
    __shared__ unsigned l_dst[MCH];            // 16 KB
    __shared__ unsigned long long l_pay[MCH];  // 32 KB
    __shared__ int sA[NBP], sB[NBP];           // 4 KB
    __shared__ int excl[NB], cur[NB], slab[NB];// 6 KB
    __shared__ int cbl[NC + 1];                // coarse bases
    __shared__ float pl[R_];
    __shared__ int s_cc0;
    const int t = threadIdx.x, blk = blockIdx.x;
    if (t < R_) pl[t] = p[t];
    if (t < NBP) sA[t] = 0;
    if (t <= NC) cbl[t] = cbase[min(t * 8, NB)];
    __syncthreads();

    const long m0 = (long)blk * MCH;
    const int lim = (int)min((long)MCH, M2_ - m0);
    if (t == 0) {                              // chunk-start coarse cell
        int cc = 0;
        while (cc < NC - 1 && cbl[cc + 1] <= (int)m0) ++cc;
        s_cc0 = cc;
    }
    __syncthreads();

    unsigned mdr[MCH / 1024];
    unsigned msrc[MCH / 1024];
    int cc = s_cc0;
    // phase 1: read records, recover src via carried walk, count dst buckets
    #pragma unroll
    for (int j = 0; j < MCH / 1024; ++j) {
        int k = t + j * 1024;
        mdr[j] = 0; msrc[j] = 0;
        if (k < lim) {
            int m = (int)(m0 + k);
            unsigned dr = __builtin_nontemporal_load(g_dr + m);
            unsigned short sl = g_sl[m];
            while (cc < NC - 1 && cbl[cc + 1] <= m) ++cc;   // 0-2 steps typ.
            msrc[j] = ((unsigned)cc << CSH) | sl;
            mdr[j] = dr;
            atomicAdd(&sA[(dr & 0xFFFFFu) >> BSH], 1);
        }
    }
    __syncthreads();
    {
        int* A = sA; int* B = sB;
        for (int off = 1; off < NBP; off <<= 1) {
            if (t < NBP) { int v = A[t]; if (t >= off) v += A[t - off]; B[t] = v; }
            __syncthreads();
            int* tmp = A; A = B; B = tmp;
        }
        if (t < NB) { int e = t ? A[t - 1] : 0; excl[t] = e; cur[t] = e; }
    }
    __syncthreads();
    // phase 2: issue gathers (coarse-window L1/L2-hot), payload, stage by dst
    uint2 xg[MCH / 1024];
    #pragma unroll
    for (int j = 0; j < MCH / 1024; ++j) {
        int k = t + j * 1024;
        if (k < lim) xg[j] = xTh[msrc[j]];
    }
    #pragma unroll
    for (int j = 0; j < MCH / 1024; ++j) {
        int k = t + j * 1024;
        if (k < lim) {
            unsigned dr = mdr[j];
            float w = pl[dr >> 20];
            __half2 h0 = __builtin_bit_cast(__half2, xg[j].x);
            __half2 h1 = __builtin_bit_cast(__half2, xg[j].y);
            unsigned plo = __builtin_bit_cast(unsigned,
                __floats2half2_rn(w * __low2float(h0), w * __high2float(h0)));
            unsigned phi = __builtin_bit_cast(unsigned,
                __floats2half2_rn(w * __low2float(h1), w * __high2float(h1)));
            unsigned dst = dr & 0xFFFFFu;
            int pos = atomicAdd(&cur[dst >> BSH], 1);
            l_dst[pos] = dst;
            l_pay[pos] = ((unsigned long long)phi << 32) | plo;
        }
    }
    __syncthreads();
    for (int c = t; c < NB; c += 1024) {
        int cnt = cur[c] - excl[c];
        slab[c] = cnt ? atomicAdd(&g_tailB[c], cnt) : 0;
    }
    __syncthreads();
    for (int s = t; s < lim; s += 1024) {
        unsigned dst = l_dst[s];
        int c = (int)(dst >> BSH);
        int pos = slab[c] + (s - excl[c]);
        g_dst2[pos] = (unsigned short)(dst & (BUCKET - 1));
        __builtin_nontemporal_store(l_pay[s], g_pay2 + pos);
    }
}

// --- accum: packed-u64 fixed point (order-independent exact integer) ---
// u64A = c0[27:0] | c1[55:28] | deg[63:56];  u64B = c2[27:0] | c3[55:28]
// comp: round(f*2^16) + 2^21 (|f|<32 clamped); deg<=255; fields stay <2^28.
__global__ __launch_bounds__(1024) void k_accum(const unsigned short* __restrict__ g_dst,
                                                const unsigned long long* __restrict__ g_pay,
                                                const int* __restrict__ cbase,
                                                float* __restrict__ y) {
    __shared__ unsigned long long accA[BUCKET];
    __shared__ unsigned long long accB[BUCKET];
    const int t = threadIdx.x, b = blockIdx.x;
    for (int i = t; i < BUCKET; i += 1024) { accA[i] = 0ull; accB[i] = 0ull; }
    __syncthreads();
    const int lo = cbase[b], hi = cbase[b + 1];
    for (int i = lo + t; i < hi; i += 1024) {
        int dl = (int)g_dst[i];
        unsigned long long pay = __builtin_nontemporal_load(g_pay + i);
        __half2 h01 = __builtin_bit_cast(__half2, (unsigned)pay);
        __half2 h23 = __builtin_bit_cast(__half2, (unsigned)(pay >> 32));
        float f0 = fminf(fmaxf(__low2float(h01),  -31.f), 31.f);
        float f1 = fminf(fmaxf(__high2float(h01), -31.f), 31.f);
        float f2 = fminf(fmaxf(__low2float(h23),  -31.f), 31.f);
        float f3 = fminf(fmaxf(__high2float(h23), -31.f), 31.f);
        unsigned e0 = (unsigned)(__float2int_rn(f0 * 65536.f) + (1 << 21));
        unsigned e1 = (unsigned)(__float2int_rn(f1 * 65536.f) + (1 << 21));
        unsigned e2 = (unsigned)(__float2int_rn(f2 * 65536.f) + (1 << 21));
        unsigned e3 = (unsigned)(__float2int_rn(f3 * 65536.f) + (1 << 21));
        unsigned long long va = (unsigned long long)e0
                              | ((unsigned long long)e1 << 28)
                              | (1ull << 56);
        unsigned long long vb = (unsigned long long)e2
                              | ((unsigned long long)e3 << 28);
        atomicAdd(&accA[dl], va);
        atomicAdd(&accB[dl], vb);
    }
    __syncthreads();
    const int base_e = b << BSH;
    for (int j = t; j < BUCKET; j += 1024) {
        int i = base_e + j;
        if (i < N_) {
            unsigned long long a = accA[j], bb = accB[j];
            long deg  = (long)(a >> 56);
            long bias = deg << 21;
            long c0 = (long)(a & 0xFFFFFFFull) - bias;
            long c1 = (long)((a >> 28) & 0xFFFFFFFull) - bias;
            long c2 = (long)(bb & 0xFFFFFFFull) - bias;
            long c3 = (long)((bb >> 28) & 0xFFFFFFFull) - bias;
            const float sc = 1.f / 65536.f;
            y[i]            = (float)c0 * sc;
            y[(long)N_ + i] = (float)c1 * sc;
            y[2L * N_ + i]  = (float)c2 * sc;
            y[3L * N_ + i]  = (float)c3 * sc;
        }
    }
}

// ---------- fallback (direct atomics; ws-independent) ----------
__global__ __launch_bounds__(256) void k_scatter_direct(const int2* __restrict__ edges,
                                                        const float* __restrict__ p,
                                                        const float* __restrict__ x,
                                                        float* __restrict__ y) {
    const long stride = (long)gridDim.x * blockDim.x;
    for (long k = (long)blockIdx.x * blockDim.x + threadIdx.x; k < RE_; k += stride) {
        int2 e = edges[k];
        float w = p[(int)(k / E_)];
        #pragma unroll
        for (int b = 0; b < 4; ++b) {
            float xu = x[(long)b * N_ + e.x];
            float xv = x[(long)b * N_ + e.y];
            atomicAdd(&y[(long)b * N_ + e.y], w * xu);
            atomicAdd(&y[(long)b * N_ + e.x], w * xv);
        }
    }
}

extern "C" void kernel_launch(void* const* d_in, const int* in_sizes, int n_in,
                              void* d_out, int out_size, void* d_ws, size_t ws_size,
                              hipStream_t stream) {
    const float* p     = (const float*)d_in[0];
    const int*   edges = (const int*)d_in[1];
    const float* x     = (const float*)d_in[2];
    float*       y     = (float*)d_out;

    const size_t pay_bytes   = (size_t)M2_ * 8;           // 102.4 MB
    const size_t dr_bytes    = (size_t)M2_ * 4;           //  51.2 MB
    const size_t xTh_bytes   = (size_t)N_ * 8;            //   8.0 MB
    const size_t bcnt_bytes  = (size_t)NB * HB * 4;       //   3.06 MB
    const size_t ctot_bytes  = (size_t)NBP * 4;
    const size_t cbase_bytes = (size_t)(NB + 1) * 4;
    const size_t tailA_bytes = (size_t)64 * 4;
    const size_t tailB_bytes = (size_t)NB * 4;
    const size_t sl_bytes    = (size_t)M2_ * 2;           //  25.6 MB
    const size_t dst2_bytes  = (size_t)M2_ * 2;           //  25.6 MB
    const size_t need = pay_bytes + dr_bytes + xTh_bytes + bcnt_bytes + ctot_bytes
                      + cbase_bytes + tailA_bytes + tailB_bytes + sl_bytes
                      + dst2_bytes + 64;

    if (ws_size >= need) {
        char* ws = (char*)d_ws;
        unsigned long long* g_pay2 = (unsigned long long*)ws;  ws += pay_bytes;
        unsigned* g_dr = (unsigned*)ws;               ws += dr_bytes;
        uint2*    xTh  = (uint2*)ws;                  ws += xTh_bytes;
        int* g_bcnt = (int*)ws;                       ws += bcnt_bytes;
        int* ctot   = (int*)ws;                       ws += ctot_bytes;
        int* cbase  = (int*)ws;                       ws += cbase_bytes;
        int* tailA  = (int*)ws;                       ws += tailA_bytes;
        int* tailB  = (int*)ws;                       ws += tailB_bytes;
        unsigned short* g_sl   = (unsigned short*)ws; ws += sl_bytes;
        unsigned short* g_dst2 = (unsigned short*)ws;

        k_transpose_h<<<(N_ + 255) / 256, 256, 0, stream>>>(x, xTh);
        k_hist<<<HB, 256, 0, stream>>>((const unsigned long long*)edges, g_bcnt);
        k_colsum<<<NB, 256, 0, stream>>>(g_bcnt, ctot);
        k_scan<<<1, 512, 0, stream>>>(ctot, cbase, tailA, tailB);
        k_srcbin<<<HB, 1024, 0, stream>>>((const unsigned long long*)edges,
                                          tailA, g_sl, g_dr);
        k_msgbuild<<<MBB, 1024, 0, stream>>>((const unsigned*)g_dr,
                                             (const unsigned short*)g_sl,
                                             cbase, tailB, p, (const uint2*)xTh,
                                             g_dst2, g_pay2);
        k_accum<<<NB, 1024, 0, stream>>>((const unsigned short*)g_dst2,
                                         (const unsigned long long*)g_pay2, cbase, y);
    } else {
        hipMemsetAsync(y, 0, (size_t)out_size * sizeof(float), stream);
        k_scatter_direct<<<8192, 256, 0, stream>>>((const int2*)edges, p, x, y);
    }
}